// Round 4
// baseline (10281.166 us; speedup 1.0000x reference)
//
#include <hip/hip_runtime.h>

#define S_LEN 2048

typedef _Float16 f16;
typedef _Float16 f16x8 __attribute__((ext_vector_type(8)));
typedef float f32x4 __attribute__((ext_vector_type(4)));
typedef unsigned u32;
typedef unsigned long long u64;
typedef unsigned u32x4v __attribute__((ext_vector_type(4)));

#define PERM_SEL 0x05040100u  // out = (lo16(a)<<16) | lo16(b)

__device__ __forceinline__ float sigf(float x) {
  x = fminf(fmaxf(x, -30.f), 30.f);
  float e = __builtin_amdgcn_exp2f(-1.44269504089f * x);
  return __builtin_amdgcn_rcpf(1.f + e);
}
__device__ __forceinline__ float tanh_fast(float x) {
  x = fminf(fmaxf(x, -15.f), 15.f);
  float e = __builtin_amdgcn_exp2f(2.88539008178f * x);  // e^(2x)
  return 1.f - 2.f * __builtin_amdgcn_rcpf(e + 1.f);
}
__device__ __forceinline__ void st_hx(u32* p, u32 v) {
  __hip_atomic_store(p, v, __ATOMIC_RELAXED, __HIP_MEMORY_SCOPE_AGENT);
}
__device__ __forceinline__ u64 ld_hx64(const u64* p) {
  return __hip_atomic_load(p, __ATOMIC_RELAXED, __HIP_MEMORY_SCOPE_AGENT);
}
__device__ __forceinline__ float swz8(float v) {
  int r = __builtin_amdgcn_ds_swizzle(__builtin_bit_cast(int, v), 0x201F);  // lane ^= 8
  return __builtin_bit_cast(float, r);
}
__device__ __forceinline__ u32 umin2(u32 a, u32 b) { return a < b ? a : b; }

// Build W16[1024][512] = [Whh | Wih] f16, bias = bih + bhh, zero hx tag words.
__global__ void convert_k(const float* __restrict__ Wih, const float* __restrict__ Whh,
                          const float* __restrict__ bih, const float* __restrict__ bhh,
                          f16* __restrict__ W16, float* __restrict__ bias,
                          u32* __restrict__ hx) {
  int i = blockIdx.x * blockDim.x + threadIdx.x;  // 524288 threads
  int n = i >> 9, k = i & 511;
  W16[i] = (f16)((k < 256) ? Whh[n * 256 + k] : Wih[n * 256 + (k - 256)]);
  if (i < 1024) bias[i] = bih[i] + bhh[i];
  if (i < 32768) hx[i] = 0u;  // replay safety: stale tags would alias
}

// Persistent LSTM: 32 wgs = 4 groups (16 batch rows, full M-tile) x 8 slices
// (32 dims). W-slice VGPR-resident. Exchange: consumers load partner h directly
// as MFMA A-fragments (4 u64 relaxed agent loads per kc), tag-in-word validity
// (min of (tag<<16|f16) preserves min tag), wave-uniform retry. No LDS h
// staging, 1 barrier/step, 2-deep x-part pipeline hides the MALL RTT.
__global__ __launch_bounds__(256, 1) void lstm_k(
    const f16* __restrict__ W16, const float* __restrict__ bias,
    const int* __restrict__ text, const float* __restrict__ embed,
    const float* __restrict__ mask, float* __restrict__ out,
    u32* __restrict__ hx) {
  __shared__ __align__(16) f16 x_sw[4][16 * 256];  // 32 KB ring, all 16 rows real

  const int tid = threadIdx.x;
  const int g = blockIdx.x & 3;       // batch group (16 rows)
  const int slice = blockIdx.x >> 2;  // 32-dim N slice
  const int b0 = g * 16;
  const int j0 = slice * 32;

  const int wv = tid >> 6;
  const int l = tid & 63;
  const int kg = l >> 4;      // k-group; D rows 4kg..4kg+3
  const int c16 = l & 15;     // A row (batch) / D col
  const int gsel = c16 >> 3;  // 0: lane's tiles hold {i,g}; 1: {f,o}
  const int d3 = c16 & 7;
  const int jloc = wv * 8 + d3;
  const int jg = j0 + jloc;
  const int asw = d3 << 3;

  const int r2 = tid >> 4;         // x-ring: batch row
  const int pd2 = (tid & 15) * 16; // x-ring: dim base (16 dims/thread)
  const int rsw2 = (r2 & 7) << 3;

  const float bi = bias[0 * 256 + jg];
  const float bf = bias[1 * 256 + jg];
  const float bg = bias[2 * 256 + jg];
  const float bo = bias[3 * 256 + jg];

  // each lane updates 2 (batch, dim) elements: all 64 lanes busy, no redundancy
  const int batchA = kg * 4 + gsel * 2;
  const int batchB = batchA + 1;
  float ccA = 0.f, ccB = 0.f;

  // resident weights: tile0 = gate gsel, tile1 = gate 2+gsel, dim jg; K=512
  f16x8 barr0[16], barr1[16];
  {
    const f16* w0 = W16 + (size_t)(gsel * 256 + jg) * 512 + kg * 8;
    const f16* w1 = W16 + (size_t)((2 + gsel) * 256 + jg) * 512 + kg * 8;
#pragma unroll
    for (int kc = 0; kc < 16; kc++) {
      barr0[kc] = *(const f16x8*)(w0 + kc * 32);
      barr1[kc] = *(const f16x8*)(w1 + kc * 32);
    }
  }

  // x ring prologue: slots 0..3 = x[0..3]
  const size_t trow2 = (size_t)(b0 + r2) * S_LEN;
#pragma unroll 1
  for (int pf = 0; pf < 4; pf++) {
    int idx = text[trow2 + pf];
    const float4* ep = (const float4*)(embed + (size_t)idx * 256 + pd2);
    float4 v0 = ep[0], v1 = ep[1], v2 = ep[2], v3 = ep[3];
    f16x8 h0 = {(f16)v0.x, (f16)v0.y, (f16)v0.z, (f16)v0.w,
                (f16)v1.x, (f16)v1.y, (f16)v1.z, (f16)v1.w};
    f16x8 h1 = {(f16)v2.x, (f16)v2.y, (f16)v2.z, (f16)v2.w,
                (f16)v3.x, (f16)v3.y, (f16)v3.z, (f16)v3.w};
    *(f16x8*)&x_sw[pf][(r2 * 256 + pd2) ^ rsw2] = h0;
    *(f16x8*)&x_sw[pf][(r2 * 256 + pd2 + 8) ^ rsw2] = h1;
  }
  float4 rxa, rxb, rxc, rxd;  // x[t+4] staging
  int idx_r;                  // text[t+5]
  {
    int idx4 = text[trow2 + 4];
    const float4* ep = (const float4*)(embed + (size_t)idx4 * 256 + pd2);
    rxa = ep[0]; rxb = ep[1]; rxc = ep[2]; rxd = ep[3];
    idx_r = text[trow2 + 5];
  }
  float mA = mask[(size_t)(b0 + batchA) * S_LEN];
  float mB = mask[(size_t)(b0 + batchB) * S_LEN];
  __syncthreads();

  auto xpart = [&](int tt, f32x4& X0, f32x4& X1) {
    const f16* xs = &x_sw[tt & 3][0];
    f32x4 a0 = {0.f, 0.f, 0.f, 0.f}, a1 = {0.f, 0.f, 0.f, 0.f};
#pragma unroll
    for (int kc = 0; kc < 8; kc++) {
      f16x8 a = *(const f16x8*)&xs[(c16 * 256 + kc * 32 + kg * 8) ^ asw];
      a0 = __builtin_amdgcn_mfma_f32_16x16x32_f16(a, barr0[8 + kc], a0, 0, 0, 0);
      a1 = __builtin_amdgcn_mfma_f32_16x16x32_f16(a, barr1[8 + kc], a1, 0, 0, 0);
    }
    X0 = a0; X1 = a1;
  };

  f32x4 XA0, XA1, XB0, XB1;
  xpart(0, XA0, XA1);
  xpart(1, XB0, XB1);

  const size_t puboff = (size_t)((g * 8 + slice) * 512 + batchA * 32 + jloc);
  const size_t pollbase = (size_t)(g * 8) * 256 + (size_t)(c16 * 16 + kg * 4);

  auto step = [&](int t, f32x4& X0, f32x4& X1, bool dopoll) {
    f32x4 acc0 = X0, acc1 = X1;
    if (dopoll) {
      const u32 expv = (u32)t;
      const u64* hb = (const u64*)hx + (size_t)(t & 1) * 8192 + pollbase;
      f16x8 frag[8];
      while (true) {
        u32 kmn[8];
#pragma unroll
        for (int kc = 0; kc < 8; kc++) {
          u64 v0 = ld_hx64(hb + kc * 256 + 0);
          u64 v1 = ld_hx64(hb + kc * 256 + 1);
          u64 v2 = ld_hx64(hb + kc * 256 + 2);
          u64 v3 = ld_hx64(hb + kc * 256 + 3);
          u32 w0 = (u32)v0, w1 = (u32)(v0 >> 32);
          u32 w2 = (u32)v1, w3 = (u32)(v1 >> 32);
          u32 w4 = (u32)v2, w5 = (u32)(v2 >> 32);
          u32 w6 = (u32)v3, w7 = (u32)(v3 >> 32);
          kmn[kc] = umin2(umin2(umin2(w0, w1), umin2(w2, w3)),
                          umin2(umin2(w4, w5), umin2(w6, w7)));
          u32x4v u;
          u.x = __builtin_amdgcn_perm(w1, w0, PERM_SEL);
          u.y = __builtin_amdgcn_perm(w3, w2, PERM_SEL);
          u.z = __builtin_amdgcn_perm(w5, w4, PERM_SEL);
          u.w = __builtin_amdgcn_perm(w7, w6, PERM_SEL);
          frag[kc] = __builtin_bit_cast(f16x8, u);
        }
        u32 mn = umin2(umin2(umin2(kmn[0], kmn[1]), umin2(kmn[2], kmn[3])),
                       umin2(umin2(kmn[4], kmn[5]), umin2(kmn[6], kmn[7])));
        if (__all((int)((mn >> 16) == expv))) break;
      }
#pragma unroll
      for (int kc = 0; kc < 8; kc++) {
        acc0 = __builtin_amdgcn_mfma_f32_16x16x32_f16(frag[kc], barr0[kc], acc0, 0, 0, 0);
        acc1 = __builtin_amdgcn_mfma_f32_16x16x32_f16(frag[kc], barr1[kc], acc1, 0, 0, 0);
      }
    }

    // in-wave gate exchange: lane d <-> d^8 swaps the other two gates
    float a0_0 = acc0[0], a0_1 = acc0[1], a0_2 = acc0[2], a0_3 = acc0[3];
    float a1_0 = acc1[0], a1_1 = acc1[1], a1_2 = acc1[2], a1_3 = acc1[3];
    float o0_0 = swz8(a0_0), o0_1 = swz8(a0_1), o0_2 = swz8(a0_2), o0_3 = swz8(a0_3);
    float o1_0 = swz8(a1_0), o1_1 = swz8(a1_1), o1_2 = swz8(a1_2), o1_3 = swz8(a1_3);

    float giA = (gsel ? o0_2 : a0_0) + bi;
    float gfA = (gsel ? a0_2 : o0_0) + bf;
    float ggA = (gsel ? o1_2 : a1_0) + bg;
    float goA = (gsel ? a1_2 : o1_0) + bo;
    float giB = (gsel ? o0_3 : a0_1) + bi;
    float gfB = (gsel ? a0_3 : o0_1) + bf;
    float ggB = (gsel ? o1_3 : a1_1) + bg;
    float goB = (gsel ? a1_3 : o1_1) + bo;

    ccA = sigf(gfA) * ccA + sigf(giA) * tanh_fast(ggA);
    float hA = sigf(goA) * tanh_fast(ccA);
    ccB = sigf(gfB) * ccB + sigf(giB) * tanh_fast(ggB);
    float hB = sigf(goB) * tanh_fast(ccB);

    // publish (tag-in-word, relaxed agent) + masked output
    const u32 tagv = (u32)(t + 1);
    u32* hbp = hx + (size_t)((t + 1) & 1) * 16384 + puboff;
    st_hx(hbp, (tagv << 16) | (u32)__builtin_bit_cast(unsigned short, (f16)hA));
    st_hx(hbp + 32, (tagv << 16) | (u32)__builtin_bit_cast(unsigned short, (f16)hB));
    out[((size_t)(b0 + batchA) * S_LEN + t) * 256 + jg] = hA * mA;
    out[((size_t)(b0 + batchB) * S_LEN + t) * 256 + jg] = hB * mB;

    __syncthreads();

    // window: RTT-hiding work (all independent of h(t+1))
    if (t + 1 < S_LEN) {
      mA = mask[(size_t)(b0 + batchA) * S_LEN + (t + 1)];
      mB = mask[(size_t)(b0 + batchB) * S_LEN + (t + 1)];
    }
    if (t + 4 < S_LEN) {  // write x[t+4] into slot t&3 (its old content was x[t])
      f16x8 h0 = {(f16)rxa.x, (f16)rxa.y, (f16)rxa.z, (f16)rxa.w,
                  (f16)rxb.x, (f16)rxb.y, (f16)rxb.z, (f16)rxb.w};
      f16x8 h1 = {(f16)rxc.x, (f16)rxc.y, (f16)rxc.z, (f16)rxc.w,
                  (f16)rxd.x, (f16)rxd.y, (f16)rxd.z, (f16)rxd.w};
      *(f16x8*)&x_sw[t & 3][(r2 * 256 + pd2) ^ rsw2] = h0;
      *(f16x8*)&x_sw[t & 3][(r2 * 256 + pd2 + 8) ^ rsw2] = h1;
    }
    if (t + 5 < S_LEN) {
      const float4* ep = (const float4*)(embed + (size_t)idx_r * 256 + pd2);
      rxa = ep[0]; rxb = ep[1]; rxc = ep[2]; rxd = ep[3];
    }
    if (t + 6 < S_LEN) idx_r = text[trow2 + t + 6];
    if (t + 2 < S_LEN) xpart(t + 2, X0, X1);  // 2-deep x pipeline
  };

  step(0, XA0, XA1, false);  // h(0) = 0: gates = x-part only
  for (int t = 1; t + 1 < S_LEN; t += 2) {
    step(t, XB0, XB1, true);
    step(t + 1, XA0, XA1, true);
  }
  step(S_LEN - 1, XB0, XB1, true);
}

extern "C" void kernel_launch(void* const* d_in, const int* in_sizes, int n_in,
                              void* d_out, int out_size, void* d_ws, size_t ws_size,
                              hipStream_t stream) {
  const int* text = (const int*)d_in[0];
  const float* mask = (const float*)d_in[1];
  // d_in[2] = len_seq: sort + inverse-sort is a no-op -> unused
  const float* embed = (const float*)d_in[3];
  const float* Wih = (const float*)d_in[4];
  const float* Whh = (const float*)d_in[5];
  const float* bih = (const float*)d_in[6];
  const float* bhh = (const float*)d_in[7];
  float* out = (float*)d_out;

  char* ws = (char*)d_ws;
  f16* W16 = (f16*)ws;                   // 1,048,576 B
  float* bias = (float*)(ws + 1048576);  // 4,096 B
  u32* hx = (u32*)(ws + 1052672);        // 131,072 B (2 x 4 x 8 x 512 u32)

  convert_k<<<2048, 256, 0, stream>>>(Wih, Whh, bih, bhh, W16, bias, hx);
  lstm_k<<<32, 256, 0, stream>>>(W16, bias, text, embed, mask, out, hx);
}

// Round 5
// 3910.649 us; speedup vs baseline: 2.6290x; 2.6290x over previous
//
#include <hip/hip_runtime.h>

#define S_LEN 2048

typedef _Float16 f16;
typedef _Float16 f16x8 __attribute__((ext_vector_type(8)));
typedef float f32x4 __attribute__((ext_vector_type(4)));
typedef unsigned u32;
typedef unsigned long long u64;
typedef unsigned u32x4v __attribute__((ext_vector_type(4)));

#define PERM_SEL 0x05040100u  // perm(a,b,SEL) = lo16(b) | lo16(a)<<16

__device__ __forceinline__ float sigf(float x) {
  x = fminf(fmaxf(x, -30.f), 30.f);
  float e = __builtin_amdgcn_exp2f(-1.44269504089f * x);
  return __builtin_amdgcn_rcpf(1.f + e);
}
__device__ __forceinline__ float tanh_fast(float x) {
  x = fminf(fmaxf(x, -15.f), 15.f);
  float e = __builtin_amdgcn_exp2f(2.88539008178f * x);  // e^(2x)
  return 1.f - 2.f * __builtin_amdgcn_rcpf(e + 1.f);
}
__device__ __forceinline__ void st_hx(u32* p, u32 v) {
  __hip_atomic_store(p, v, __ATOMIC_RELAXED, __HIP_MEMORY_SCOPE_AGENT);
}
__device__ __forceinline__ u64 ld_hx64(const u64* p) {
  return __hip_atomic_load(p, __ATOMIC_RELAXED, __HIP_MEMORY_SCOPE_AGENT);
}
__device__ __forceinline__ float swz8(float v) {
  int r = __builtin_amdgcn_ds_swizzle(__builtin_bit_cast(int, v), 0x201F);  // lane ^= 8
  return __builtin_bit_cast(float, r);
}
__device__ __forceinline__ u32 umin2(u32 a, u32 b) { return a < b ? a : b; }

// Build W16[1024][512] = [Whh | Wih] f16, bias = bih + bhh, zero hx tag words.
__global__ void convert_k(const float* __restrict__ Wih, const float* __restrict__ Whh,
                          const float* __restrict__ bih, const float* __restrict__ bhh,
                          f16* __restrict__ W16, float* __restrict__ bias,
                          u32* __restrict__ hx) {
  int i = blockIdx.x * blockDim.x + threadIdx.x;  // 524288 threads
  int n = i >> 9, k = i & 511;
  W16[i] = (f16)((k < 256) ? Whh[n * 256 + k] : Wih[n * 256 + (k - 256)]);
  if (i < 1024) bias[i] = bih[i] + bhh[i];
  if (i < 65536) hx[i] = 0u;  // 4 parity buffers; replay safety
}

// Pre-convert embedding table to f16 (8,192,000 elems, 8 per thread).
__global__ void convert_embed_k(const float* __restrict__ e, f16* __restrict__ e16) {
  int i = (blockIdx.x * 256 + threadIdx.x) * 8;
  float4 a = *(const float4*)(e + i);
  float4 b = *(const float4*)(e + i + 4);
  f16x8 v = {(f16)a.x, (f16)a.y, (f16)a.z, (f16)a.w,
             (f16)b.x, (f16)b.y, (f16)b.z, (f16)b.w};
  *(f16x8*)(e16 + i) = v;
}

// Persistent LSTM: 32 wgs = 4 groups (16 batch rows, full M tile) x 8 slices
// (32 dims). W-slice resident in VGPRs. Exchange: publish tagged (tag<<16|f16)
// words with relaxed agent atomics into 4-deep parity buffers; consumers poll
// 8 u64/lane (16 dims of one batch row), min-tree tag check, LDS gather.
// One barrier/step; 2-deep x-part pipeline hides the MALL RTT.
template <int EMB16>
__global__ __launch_bounds__(256, 1) void lstm_k(
    const f16* __restrict__ W16, const float* __restrict__ bias,
    const int* __restrict__ text, const float* __restrict__ embedf,
    const f16* __restrict__ embed16, const float* __restrict__ mask,
    float* __restrict__ out, u32* __restrict__ hx) {
  __shared__ __align__(16) f16 x_sw[4][16 * 256];  // 32 KB ring
  __shared__ __align__(16) f16 h_sw[2][16 * 256];  // 16 KB parity buffers

  const int tid = threadIdx.x;
  const int g = blockIdx.x & 3;       // batch group (16 rows)
  const int slice = blockIdx.x >> 2;  // 32-dim N slice
  const int b0 = g * 16;
  const int j0 = slice * 32;

  const int wv = tid >> 6;
  const int l = tid & 63;
  const int kg = l >> 4;      // k-group; D rows 4kg..4kg+3
  const int c16 = l & 15;     // A row (batch) / D col
  const int gsel = c16 >> 3;  // 0: lane's tiles hold {i,g}; 1: {f,o}
  const int d3 = c16 & 7;
  const int jloc = wv * 8 + d3;
  const int jg = j0 + jloc;
  const int asw = d3 << 3;

  // stage/poll/gather mapping: 16 threads per batch row, 16 dims each
  const int r2 = tid >> 4;
  const int pd2 = (tid & 15) * 16;
  const int rsw2 = (r2 & 7) << 3;
  const int ownlane = ((pd2 >> 5) == slice);  // lane's 16 dims are own slice

  const float bi = bias[0 * 256 + jg];
  const float bf = bias[1 * 256 + jg];
  const float bg = bias[2 * 256 + jg];
  const float bo = bias[3 * 256 + jg];

  // each lane updates 2 (batch, dim) elements: all 64 lanes busy
  const int batchA = kg * 4 + gsel * 2;
  const int batchB = batchA + 1;
  float ccA = 0.f, ccB = 0.f;

  // zero both h parity buffers (h0 = 0)
  {
    f16x8 z = {(f16)0.f, (f16)0.f, (f16)0.f, (f16)0.f,
               (f16)0.f, (f16)0.f, (f16)0.f, (f16)0.f};
    *(f16x8*)&h_sw[0][tid * 16] = z;
    *(f16x8*)&h_sw[0][tid * 16 + 8] = z;
    *(f16x8*)&h_sw[1][tid * 16] = z;
    *(f16x8*)&h_sw[1][tid * 16 + 8] = z;
  }

  // resident weights: tile0 = gate gsel, tile1 = gate 2+gsel, dim jg; K=512
  f16x8 barr0[16], barr1[16];
  {
    const f16* w0 = W16 + (size_t)(gsel * 256 + jg) * 512 + kg * 8;
    const f16* w1 = W16 + (size_t)((2 + gsel) * 256 + jg) * 512 + kg * 8;
#pragma unroll
    for (int kc = 0; kc < 16; kc++) {
      barr0[kc] = *(const f16x8*)(w0 + kc * 32);
      barr1[kc] = *(const f16x8*)(w1 + kc * 32);
    }
  }

  // x ring prologue: slots 0..3 = x[0..3]
  const size_t trow2 = (size_t)(b0 + r2) * S_LEN;
  f16x8 sxa, sxb;       // staged x[t+4] (EMB16 path)
  float4 rxa, rxb, rxc, rxd;  // staged x[t+4] (f32 path)
  int idx_r;            // text[t+5]
#pragma unroll 1
  for (int pf = 0; pf < 4; pf++) {
    int idx = text[trow2 + pf];
    f16x8 h0, h1;
    if (EMB16) {
      const f16x8* ep = (const f16x8*)(embed16 + (size_t)idx * 256 + pd2);
      h0 = ep[0];
      h1 = ep[1];
    } else {
      const float4* ep = (const float4*)(embedf + (size_t)idx * 256 + pd2);
      float4 v0 = ep[0], v1 = ep[1], v2 = ep[2], v3 = ep[3];
      h0 = (f16x8){(f16)v0.x, (f16)v0.y, (f16)v0.z, (f16)v0.w,
                   (f16)v1.x, (f16)v1.y, (f16)v1.z, (f16)v1.w};
      h1 = (f16x8){(f16)v2.x, (f16)v2.y, (f16)v2.z, (f16)v2.w,
                   (f16)v3.x, (f16)v3.y, (f16)v3.z, (f16)v3.w};
    }
    *(f16x8*)&x_sw[pf][(r2 * 256 + pd2) ^ rsw2] = h0;
    *(f16x8*)&x_sw[pf][(r2 * 256 + pd2 + 8) ^ rsw2] = h1;
  }
  {
    int idx4 = text[trow2 + 4];
    if (EMB16) {
      const f16x8* ep = (const f16x8*)(embed16 + (size_t)idx4 * 256 + pd2);
      sxa = ep[0];
      sxb = ep[1];
    } else {
      const float4* ep = (const float4*)(embedf + (size_t)idx4 * 256 + pd2);
      rxa = ep[0]; rxb = ep[1]; rxc = ep[2]; rxd = ep[3];
    }
    idx_r = text[trow2 + 5];
  }
  float mA = mask[(size_t)(b0 + batchA) * S_LEN];
  float mB = mask[(size_t)(b0 + batchB) * S_LEN];
  __syncthreads();

  auto xpart = [&](int tt, f32x4& X0, f32x4& X1) {
    const f16* xs = &x_sw[tt & 3][0];
    f32x4 a0 = {0.f, 0.f, 0.f, 0.f}, a1 = {0.f, 0.f, 0.f, 0.f};
#pragma unroll
    for (int kc = 0; kc < 8; kc++) {
      f16x8 a = *(const f16x8*)&xs[(c16 * 256 + kc * 32 + kg * 8) ^ asw];
      a0 = __builtin_amdgcn_mfma_f32_16x16x32_f16(a, barr0[8 + kc], a0, 0, 0, 0);
      a1 = __builtin_amdgcn_mfma_f32_16x16x32_f16(a, barr1[8 + kc], a1, 0, 0, 0);
    }
    X0 = a0; X1 = a1;
  };

  f32x4 XA0, XA1, XB0, XB1;
  xpart(0, XA0, XA1);
  xpart(1, XB0, XB1);

  const size_t puboff = (size_t)((g * 8 + slice) * 512 + batchA * 32 + jloc);
  // poll base (u64 units): words (g*8+s)*512 + r2*32 + (pd2&31), halved
  const size_t pollb64 =
      (size_t)((g * 8 + (pd2 >> 5)) * 256 + r2 * 16 + ((pd2 & 31) >> 1));

  auto step = [&](int t, f32x4& X0, f32x4& X1) {
    // h-part MFMA from parity LDS buffer (zeros at t=0)
    const f16* hs = &h_sw[t & 1][0];
    f32x4 acc0 = X0, acc1 = X1;
#pragma unroll
    for (int kc = 0; kc < 8; kc++) {
      f16x8 a = *(const f16x8*)&hs[(c16 * 256 + kc * 32 + kg * 8) ^ asw];
      acc0 = __builtin_amdgcn_mfma_f32_16x16x32_f16(a, barr0[kc], acc0, 0, 0, 0);
      acc1 = __builtin_amdgcn_mfma_f32_16x16x32_f16(a, barr1[kc], acc1, 0, 0, 0);
    }

    // in-wave gate exchange: lane d <-> d^8 swaps the other two gates
    float a0_0 = acc0[0], a0_1 = acc0[1], a0_2 = acc0[2], a0_3 = acc0[3];
    float a1_0 = acc1[0], a1_1 = acc1[1], a1_2 = acc1[2], a1_3 = acc1[3];
    float o0_0 = swz8(a0_0), o0_1 = swz8(a0_1), o0_2 = swz8(a0_2), o0_3 = swz8(a0_3);
    float o1_0 = swz8(a1_0), o1_1 = swz8(a1_1), o1_2 = swz8(a1_2), o1_3 = swz8(a1_3);

    float giA = (gsel ? o0_2 : a0_0) + bi;
    float gfA = (gsel ? a0_2 : o0_0) + bf;
    float ggA = (gsel ? o1_2 : a1_0) + bg;
    float goA = (gsel ? a1_2 : o1_0) + bo;
    float giB = (gsel ? o0_3 : a0_1) + bi;
    float gfB = (gsel ? a0_3 : o0_1) + bf;
    float ggB = (gsel ? o1_3 : a1_1) + bg;
    float goB = (gsel ? a1_3 : o1_1) + bo;

    ccA = sigf(gfA) * ccA + sigf(giA) * tanh_fast(ggA);
    float hA = sigf(goA) * tanh_fast(ccA);
    ccB = sigf(gfB) * ccB + sigf(giB) * tanh_fast(ggB);
    float hB = sigf(goB) * tanh_fast(ccB);

    // publish (tag-in-word, relaxed agent atomics, 4-deep parity)
    const u32 tagv = (u32)(t + 1);
    u32* hbp = hx + (size_t)((t + 1) & 3) * 16384 + puboff;
    st_hx(hbp, (tagv << 16) | (u32)__builtin_bit_cast(unsigned short, (f16)hA));
    st_hx(hbp + 32, (tagv << 16) | (u32)__builtin_bit_cast(unsigned short, (f16)hB));

    // masked output + own h into next parity LDS buffer
    f16* hd = &h_sw[(t + 1) & 1][0];
    out[((size_t)(b0 + batchA) * S_LEN + t) * 256 + jg] = hA * mA;
    out[((size_t)(b0 + batchB) * S_LEN + t) * 256 + jg] = hB * mB;
    hd[(batchA * 256 + jg) ^ ((batchA & 7) << 3)] = (f16)hA;
    hd[(batchB * 256 + jg) ^ ((batchB & 7) << 3)] = (f16)hB;

    // window: RTT-hiding work (independent of partners' h)
    if (t + 1 < S_LEN) {
      mA = mask[(size_t)(b0 + batchA) * S_LEN + (t + 1)];
      mB = mask[(size_t)(b0 + batchB) * S_LEN + (t + 1)];
    }
    if (t + 4 < S_LEN) {  // write staged x[t+4] into slot t&3 (x[t] consumed)
      f16x8 h0, h1;
      if (EMB16) {
        h0 = sxa;
        h1 = sxb;
      } else {
        h0 = (f16x8){(f16)rxa.x, (f16)rxa.y, (f16)rxa.z, (f16)rxa.w,
                     (f16)rxb.x, (f16)rxb.y, (f16)rxb.z, (f16)rxb.w};
        h1 = (f16x8){(f16)rxc.x, (f16)rxc.y, (f16)rxc.z, (f16)rxc.w,
                     (f16)rxd.x, (f16)rxd.y, (f16)rxd.z, (f16)rxd.w};
      }
      *(f16x8*)&x_sw[t & 3][(r2 * 256 + pd2) ^ rsw2] = h0;
      *(f16x8*)&x_sw[t & 3][(r2 * 256 + pd2 + 8) ^ rsw2] = h1;
    }
    if (t + 5 < S_LEN) {
      if (EMB16) {
        const f16x8* ep = (const f16x8*)(embed16 + (size_t)idx_r * 256 + pd2);
        sxa = ep[0];
        sxb = ep[1];
      } else {
        const float4* ep = (const float4*)(embedf + (size_t)idx_r * 256 + pd2);
        rxa = ep[0]; rxb = ep[1]; rxc = ep[2]; rxd = ep[3];
      }
    }
    if (t + 6 < S_LEN) idx_r = text[trow2 + t + 6];
    if (t + 2 < S_LEN) xpart(t + 2, X0, X1);  // 2-deep x pipeline

    // poll partners' h(t+1): 8 u64 tagged words per non-own lane
    if (t + 1 < S_LEN) {
      const u32 expv = (u32)(t + 1);
      const u64* hb = (const u64*)hx + (size_t)((t + 1) & 3) * 8192 + pollb64;
      u32 w0, w1, w2, w3, w4, w5, w6, w7, w8, w9, wa, wb, wc, wd, we, wf;
      int done;
      do {
        done = 1;
        if (!ownlane) {
          u64 v0 = ld_hx64(hb + 0), v1 = ld_hx64(hb + 1);
          u64 v2 = ld_hx64(hb + 2), v3 = ld_hx64(hb + 3);
          u64 v4 = ld_hx64(hb + 4), v5 = ld_hx64(hb + 5);
          u64 v6 = ld_hx64(hb + 6), v7 = ld_hx64(hb + 7);
          w0 = (u32)v0; w1 = (u32)(v0 >> 32);
          w2 = (u32)v1; w3 = (u32)(v1 >> 32);
          w4 = (u32)v2; w5 = (u32)(v2 >> 32);
          w6 = (u32)v3; w7 = (u32)(v3 >> 32);
          w8 = (u32)v4; w9 = (u32)(v4 >> 32);
          wa = (u32)v5; wb = (u32)(v5 >> 32);
          wc = (u32)v6; wd = (u32)(v6 >> 32);
          we = (u32)v7; wf = (u32)(v7 >> 32);
          u32 mn = umin2(
              umin2(umin2(umin2(w0, w1), umin2(w2, w3)),
                    umin2(umin2(w4, w5), umin2(w6, w7))),
              umin2(umin2(umin2(w8, w9), umin2(wa, wb)),
                    umin2(umin2(wc, wd), umin2(we, wf))));
          done = (int)((mn >> 16) == expv);
        }
      } while (!__all(done));

      // gather 16 f16 -> h_sw parity buffer (own slice written by update lanes)
      if (!ownlane) {
        u32x4v pA, pB;
        pA.x = __builtin_amdgcn_perm(w1, w0, PERM_SEL);
        pA.y = __builtin_amdgcn_perm(w3, w2, PERM_SEL);
        pA.z = __builtin_amdgcn_perm(w5, w4, PERM_SEL);
        pA.w = __builtin_amdgcn_perm(w7, w6, PERM_SEL);
        pB.x = __builtin_amdgcn_perm(w9, w8, PERM_SEL);
        pB.y = __builtin_amdgcn_perm(wb, wa, PERM_SEL);
        pB.z = __builtin_amdgcn_perm(wd, wc, PERM_SEL);
        pB.w = __builtin_amdgcn_perm(wf, we, PERM_SEL);
        *(u32x4v*)&hd[(r2 * 256 + pd2) ^ rsw2] = pA;
        *(u32x4v*)&hd[(r2 * 256 + pd2 + 8) ^ rsw2] = pB;
      }
    }
    __syncthreads();
  };

  for (int t = 0; t + 1 < S_LEN; t += 2) {
    step(t, XA0, XA1);
    step(t + 1, XB0, XB1);
  }
}

extern "C" void kernel_launch(void* const* d_in, const int* in_sizes, int n_in,
                              void* d_out, int out_size, void* d_ws, size_t ws_size,
                              hipStream_t stream) {
  const int* text = (const int*)d_in[0];
  const float* mask = (const float*)d_in[1];
  // d_in[2] = len_seq: sort + inverse-sort is a no-op -> unused
  const float* embed = (const float*)d_in[3];
  const float* Wih = (const float*)d_in[4];
  const float* Whh = (const float*)d_in[5];
  const float* bih = (const float*)d_in[6];
  const float* bhh = (const float*)d_in[7];
  float* out = (float*)d_out;

  char* ws = (char*)d_ws;
  f16* W16 = (f16*)ws;                    // 1,048,576 B
  float* bias = (float*)(ws + 1048576);   // 4,096 B
  u32* hx = (u32*)(ws + 1052672);         // 262,144 B (4 parity x 16384 u32)
  f16* embed16 = (f16*)(ws + 1314816);    // 16,384,000 B
  const size_t WS_NEED = 1314816 + 16384000;

  convert_k<<<2048, 256, 0, stream>>>(Wih, Whh, bih, bhh, W16, bias, hx);
  if (ws_size >= WS_NEED) {
    convert_embed_k<<<4000, 256, 0, stream>>>(embed, embed16);
    lstm_k<1><<<32, 256, 0, stream>>>(W16, bias, text, embed, embed16, mask, out, hx);
  } else {
    lstm_k<0><<<32, 256, 0, stream>>>(W16, bias, text, embed, embed16, mask, out, hx);
  }
}

// Round 6
// 3905.140 us; speedup vs baseline: 2.6327x; 1.0014x over previous
//
#include <hip/hip_runtime.h>

#define S_LEN 2048
#define HROW 264            // padded LDS row stride in f16 (256 + 8)
#define HBUF (16 * HROW)    // one 16-batch buffer

typedef _Float16 f16;
typedef _Float16 f16x8 __attribute__((ext_vector_type(8)));
typedef float f32x4 __attribute__((ext_vector_type(4)));
typedef unsigned u32;
typedef unsigned long long u64;

#define PERM_SEL 0x05040100u  // perm(a,b,SEL) = lo16(b) | lo16(a)<<16

__device__ __forceinline__ float sigf(float x) {
  x = fminf(fmaxf(x, -30.f), 30.f);
  float e = __builtin_amdgcn_exp2f(-1.44269504089f * x);
  return __builtin_amdgcn_rcpf(1.f + e);
}
__device__ __forceinline__ float tanh_fast(float x) {
  x = fminf(fmaxf(x, -15.f), 15.f);
  float e = __builtin_amdgcn_exp2f(2.88539008178f * x);  // e^(2x)
  return 1.f - 2.f * __builtin_amdgcn_rcpf(e + 1.f);
}
__device__ __forceinline__ void st_hx(u32* p, u32 v) {
  __hip_atomic_store(p, v, __ATOMIC_RELAXED, __HIP_MEMORY_SCOPE_AGENT);
}
__device__ __forceinline__ u64 ld_hx64(const u64* p) {
  return __hip_atomic_load(p, __ATOMIC_RELAXED, __HIP_MEMORY_SCOPE_AGENT);
}
__device__ __forceinline__ u32 umin2(u32 a, u32 b) { return a < b ? a : b; }

// Build W16[1024][512] = [Whh | Wih] f16, bias = bih + bhh, zero hx tag words.
__global__ void convert_k(const float* __restrict__ Wih, const float* __restrict__ Whh,
                          const float* __restrict__ bih, const float* __restrict__ bhh,
                          f16* __restrict__ W16, float* __restrict__ bias,
                          u32* __restrict__ hx) {
  int i = blockIdx.x * blockDim.x + threadIdx.x;  // 524288 threads
  int n = i >> 9, k = i & 511;
  W16[i] = (f16)((k < 256) ? Whh[n * 256 + k] : Wih[n * 256 + (k - 256)]);
  if (i < 1024) bias[i] = bih[i] + bhh[i];
  if (i < 65536) hx[i] = 0u;  // 4 parity buffers; replay safety
}

// Pre-convert embedding table to f16 (8,192,000 elems, 8 per thread).
__global__ void convert_embed_k(const float* __restrict__ e, f16* __restrict__ e16) {
  int i = (blockIdx.x * 256 + threadIdx.x) * 8;
  float4 a = *(const float4*)(e + i);
  float4 b = *(const float4*)(e + i + 4);
  f16x8 v = {(f16)a.x, (f16)a.y, (f16)a.z, (f16)a.w,
             (f16)b.x, (f16)b.y, (f16)b.z, (f16)b.w};
  *(f16x8*)(e16 + i) = v;
}

// Persistent LSTM: 16 wgs = 4 groups (16 batches) x 4 quarter-wgs (64 dims).
// wg = 256 thr / 4 waves, 1 wave/SIMD (512-VGPR budget): W-slice = 256 VGPRs.
// Wave tile layout = gate-per-tile: all 4 gates of a (batch,dim) live in one
// lane's accumulators -> straight-line update, no shuffles. Exchange: tagged
// (tag<<16|f16) relaxed agent words, 4-deep parity; probe = 6 u64/thread.
template <int EMB16>
__global__ __launch_bounds__(256, 1) void lstm_k(
    const f16* __restrict__ W16, const float* __restrict__ bias,
    const int* __restrict__ text, const float* __restrict__ embedf,
    const f16* __restrict__ embed16, const float* __restrict__ mask,
    float* __restrict__ out, u32* __restrict__ hx) {
  __shared__ __align__(16) f16 x_sw[4][HBUF];  // 33 KB ring (padded rows)
  __shared__ __align__(16) f16 h_sw[2][HBUF];  // 16.5 KB parity buffers

  const int tid = threadIdx.x;
  const int g = blockIdx.x & 3;     // batch group (16 rows)
  const int myq = blockIdx.x >> 2;  // 64-dim quarter
  const int b0 = g * 16;

  const int wv = tid >> 6;
  const int l = tid & 63;
  const int kg = l >> 4;   // k-group; D rows (batches) 4kg..4kg+3
  const int c16 = l & 15;  // A row (batch) / D col (dim)
  const int jg = myq * 64 + wv * 16 + c16;  // global dim of this lane

  // staging / poll / gather mapping: 16 threads per batch row
  const int r2 = tid >> 4;   // batch 0..15
  const int dl = tid & 15;   // sub-index
  const int pd2 = dl * 16;   // staging dim base (16 dims/thread)

  // zero both h parity buffers (h0 = 0)
  {
    f16x8 z = {(f16)0.f, (f16)0.f, (f16)0.f, (f16)0.f,
               (f16)0.f, (f16)0.f, (f16)0.f, (f16)0.f};
    for (int i = tid; i < 2 * HBUF / 8; i += 256) ((f16x8*)h_sw)[i] = z;
  }

  const float bi0 = bias[0 * 256 + jg];
  const float bi1 = bias[1 * 256 + jg];
  const float bi2 = bias[2 * 256 + jg];
  const float bi3 = bias[3 * 256 + jg];
  float cc0 = 0.f, cc1 = 0.f, cc2 = 0.f, cc3 = 0.f;

  // resident W: barr[gate][kc], rows n = gate*256 + jg, k = kc*32 + kg*8
  f16x8 barr[4][16];
#pragma unroll
  for (int gg = 0; gg < 4; gg++) {
    const f16* w = W16 + (size_t)(gg * 256 + jg) * 512 + kg * 8;
#pragma unroll
    for (int kc = 0; kc < 16; kc++) barr[gg][kc] = *(const f16x8*)(w + kc * 32);
  }

  // x ring prologue: slots 0..3 = x[0..3]
  const size_t trow2 = (size_t)(b0 + r2) * S_LEN;
  f16x8 sxa, sxb;             // staged x[t+4] (EMB16)
  float4 rxa, rxb, rxc, rxd;  // staged x[t+4] (f32 fallback)
  int idx_r;                  // text[t+5]
#pragma unroll 1
  for (int pf = 0; pf < 4; pf++) {
    int idx = text[trow2 + pf];
    f16x8 h0, h1;
    if (EMB16) {
      const f16x8* ep = (const f16x8*)(embed16 + (size_t)idx * 256 + pd2);
      h0 = ep[0];
      h1 = ep[1];
    } else {
      const float4* ep = (const float4*)(embedf + (size_t)idx * 256 + pd2);
      float4 v0 = ep[0], v1 = ep[1], v2 = ep[2], v3 = ep[3];
      h0 = (f16x8){(f16)v0.x, (f16)v0.y, (f16)v0.z, (f16)v0.w,
                   (f16)v1.x, (f16)v1.y, (f16)v1.z, (f16)v1.w};
      h1 = (f16x8){(f16)v2.x, (f16)v2.y, (f16)v2.z, (f16)v2.w,
                   (f16)v3.x, (f16)v3.y, (f16)v3.z, (f16)v3.w};
    }
    *(f16x8*)&x_sw[pf][r2 * HROW + pd2] = h0;
    *(f16x8*)&x_sw[pf][r2 * HROW + pd2 + 8] = h1;
  }
  {
    int idx4 = text[trow2 + 4];
    if (EMB16) {
      const f16x8* ep = (const f16x8*)(embed16 + (size_t)idx4 * 256 + pd2);
      sxa = ep[0];
      sxb = ep[1];
    } else {
      const float4* ep = (const float4*)(embedf + (size_t)idx4 * 256 + pd2);
      rxa = ep[0]; rxb = ep[1]; rxc = ep[2]; rxd = ep[3];
    }
    idx_r = text[trow2 + 5];
  }
  float m0 = mask[(size_t)(b0 + kg * 4 + 0) * S_LEN];
  float m1 = mask[(size_t)(b0 + kg * 4 + 1) * S_LEN];
  float m2 = mask[(size_t)(b0 + kg * 4 + 2) * S_LEN];
  float m3 = mask[(size_t)(b0 + kg * 4 + 3) * S_LEN];
  __syncthreads();

  auto xpart = [&](int tt, f32x4 (&X)[4]) {
    const f16* xs = &x_sw[tt & 3][0];
    f32x4 t0 = {0.f, 0.f, 0.f, 0.f}, t1 = t0, t2 = t0, t3 = t0;
#pragma unroll
    for (int kc = 0; kc < 8; kc++) {
      f16x8 a = *(const f16x8*)&xs[c16 * HROW + kc * 32 + kg * 8];
      t0 = __builtin_amdgcn_mfma_f32_16x16x32_f16(a, barr[0][8 + kc], t0, 0, 0, 0);
      t1 = __builtin_amdgcn_mfma_f32_16x16x32_f16(a, barr[1][8 + kc], t1, 0, 0, 0);
      t2 = __builtin_amdgcn_mfma_f32_16x16x32_f16(a, barr[2][8 + kc], t2, 0, 0, 0);
      t3 = __builtin_amdgcn_mfma_f32_16x16x32_f16(a, barr[3][8 + kc], t3, 0, 0, 0);
    }
    X[0] = t0; X[1] = t1; X[2] = t2; X[3] = t3;
  };

  f32x4 XA[4], XB[4];
  xpart(0, XA);
  xpart(1, XB);

  // partner quarters
  const int qa = 0 + (0 >= myq);
  const int qb = 1 + (1 >= myq);
  const int qc = 2 + (2 >= myq);

  auto step = [&](int t, f32x4 (&X)[4]) {
    // h-part MFMA (critical): acc = xacc + h_t @ Whh-slice^T
    const f16* hs = &h_sw[t & 1][0];
    f32x4 a0 = X[0], a1 = X[1], a2 = X[2], a3 = X[3];
#pragma unroll
    for (int kc = 0; kc < 8; kc++) {
      f16x8 a = *(const f16x8*)&hs[c16 * HROW + kc * 32 + kg * 8];
      a0 = __builtin_amdgcn_mfma_f32_16x16x32_f16(a, barr[0][kc], a0, 0, 0, 0);
      a1 = __builtin_amdgcn_mfma_f32_16x16x32_f16(a, barr[1][kc], a1, 0, 0, 0);
      a2 = __builtin_amdgcn_mfma_f32_16x16x32_f16(a, barr[2][kc], a2, 0, 0, 0);
      a3 = __builtin_amdgcn_mfma_f32_16x16x32_f16(a, barr[3][kc], a3, 0, 0, 0);
    }

    f16* hd = &h_sw[(t + 1) & 1][0];
    const u32 tagv = (u32)(t + 1);
    u32* hb = hx + (size_t)((t + 1) & 3) * 16384 + (size_t)g * 4096 + jg;

    // straight-line update: all 4 gates of (batch 4kg+i, dim jg) are in-lane
#pragma unroll
    for (int i = 0; i < 4; i++) {
      float gi = ((i == 0) ? a0[0] : (i == 1) ? a0[1] : (i == 2) ? a0[2] : a0[3]) + bi0;
      float gf = ((i == 0) ? a1[0] : (i == 1) ? a1[1] : (i == 2) ? a1[2] : a1[3]) + bi1;
      float gG = ((i == 0) ? a2[0] : (i == 1) ? a2[1] : (i == 2) ? a2[2] : a2[3]) + bi2;
      float go = ((i == 0) ? a3[0] : (i == 1) ? a3[1] : (i == 2) ? a3[2] : a3[3]) + bi3;
      float& cc = (i == 0) ? cc0 : (i == 1) ? cc1 : (i == 2) ? cc2 : cc3;
      float mv = (i == 0) ? m0 : (i == 1) ? m1 : (i == 2) ? m2 : m3;
      cc = sigf(gf) * cc + sigf(gi) * tanh_fast(gG);
      float h = sigf(go) * tanh_fast(cc);
      int b = kg * 4 + i;
      st_hx(hb + b * 256, (tagv << 16) | (u32)__builtin_bit_cast(unsigned short, (f16)h));
      out[((size_t)(b0 + b) * S_LEN + t) * 256 + jg] = h * mv;
      hd[b * HROW + jg] = (f16)h;
    }

    if (t + 1 < S_LEN) {
      // ---- RTT-hiding window (independent of partners' h) ----
      m0 = mask[(size_t)(b0 + kg * 4 + 0) * S_LEN + (t + 1)];
      m1 = mask[(size_t)(b0 + kg * 4 + 1) * S_LEN + (t + 1)];
      m2 = mask[(size_t)(b0 + kg * 4 + 2) * S_LEN + (t + 1)];
      m3 = mask[(size_t)(b0 + kg * 4 + 3) * S_LEN + (t + 1)];
      if (t + 4 < S_LEN) {  // write staged x[t+4] into slot t&3 (x[t] consumed)
        f16x8 h0, h1;
        if (EMB16) {
          h0 = sxa;
          h1 = sxb;
        } else {
          h0 = (f16x8){(f16)rxa.x, (f16)rxa.y, (f16)rxa.z, (f16)rxa.w,
                       (f16)rxb.x, (f16)rxb.y, (f16)rxb.z, (f16)rxb.w};
          h1 = (f16x8){(f16)rxc.x, (f16)rxc.y, (f16)rxc.z, (f16)rxc.w,
                       (f16)rxd.x, (f16)rxd.y, (f16)rxd.z, (f16)rxd.w};
        }
        *(f16x8*)&x_sw[t & 3][r2 * HROW + pd2] = h0;
        *(f16x8*)&x_sw[t & 3][r2 * HROW + pd2 + 8] = h1;
      }
      if (t + 5 < S_LEN) {
        if (EMB16) {
          const f16x8* ep = (const f16x8*)(embed16 + (size_t)idx_r * 256 + pd2);
          sxa = ep[0];
          sxb = ep[1];
        } else {
          const float4* ep = (const float4*)(embedf + (size_t)idx_r * 256 + pd2);
          rxa = ep[0]; rxb = ep[1]; rxc = ep[2]; rxd = ep[3];
        }
      }
      if (t + 6 < S_LEN) idx_r = text[trow2 + t + 6];
      if (t + 2 < S_LEN) xpart(t + 2, X);  // 2-deep x pipeline

      // ---- poll partners' h(t+1): 6 u64 tagged words per thread ----
      const u64* hp = (const u64*)hx + (size_t)((t + 1) & 3) * 8192 +
                      (size_t)g * 2048 + (size_t)r2 * 128 + dl * 2;
      u32 wa0, wa1, wa2, wa3, wb0, wb1, wb2, wb3, wc0, wc1, wc2, wc3;
      int done;
      do {
        u64 va0 = ld_hx64(hp + qa * 32 + 0), va1 = ld_hx64(hp + qa * 32 + 1);
        u64 vb0 = ld_hx64(hp + qb * 32 + 0), vb1 = ld_hx64(hp + qb * 32 + 1);
        u64 vc0 = ld_hx64(hp + qc * 32 + 0), vc1 = ld_hx64(hp + qc * 32 + 1);
        wa0 = (u32)va0; wa1 = (u32)(va0 >> 32); wa2 = (u32)va1; wa3 = (u32)(va1 >> 32);
        wb0 = (u32)vb0; wb1 = (u32)(vb0 >> 32); wb2 = (u32)vb1; wb3 = (u32)(vb1 >> 32);
        wc0 = (u32)vc0; wc1 = (u32)(vc0 >> 32); wc2 = (u32)vc1; wc3 = (u32)(vc1 >> 32);
        u32 mn = umin2(umin2(umin2(wa0, wa1), umin2(wa2, wa3)),
                       umin2(umin2(umin2(wb0, wb1), umin2(wb2, wb3)),
                             umin2(umin2(wc0, wc1), umin2(wc2, wc3))));
        done = (int)((mn >> 16) == tagv);
      } while (!__all(done));

      // gather 12 f16 -> h_sw parity buffer (own quarter written by update)
      u32 pa0 = __builtin_amdgcn_perm(wa1, wa0, PERM_SEL);
      u32 pa1 = __builtin_amdgcn_perm(wa3, wa2, PERM_SEL);
      u32 pb0 = __builtin_amdgcn_perm(wb1, wb0, PERM_SEL);
      u32 pb1 = __builtin_amdgcn_perm(wb3, wb2, PERM_SEL);
      u32 pc0 = __builtin_amdgcn_perm(wc1, wc0, PERM_SEL);
      u32 pc1 = __builtin_amdgcn_perm(wc3, wc2, PERM_SEL);
      *(u64*)&hd[r2 * HROW + qa * 64 + dl * 4] = ((u64)pa1 << 32) | pa0;
      *(u64*)&hd[r2 * HROW + qb * 64 + dl * 4] = ((u64)pb1 << 32) | pb0;
      *(u64*)&hd[r2 * HROW + qc * 64 + dl * 4] = ((u64)pc1 << 32) | pc0;
    }
    __syncthreads();
  };

  for (int t = 0; t < S_LEN; t += 2) {
    step(t, XA);
    step(t + 1, XB);
  }
}

extern "C" void kernel_launch(void* const* d_in, const int* in_sizes, int n_in,
                              void* d_out, int out_size, void* d_ws, size_t ws_size,
                              hipStream_t stream) {
  const int* text = (const int*)d_in[0];
  const float* mask = (const float*)d_in[1];
  // d_in[2] = len_seq: sort + inverse-sort is a no-op -> unused
  const float* embed = (const float*)d_in[3];
  const float* Wih = (const float*)d_in[4];
  const float* Whh = (const float*)d_in[5];
  const float* bih = (const float*)d_in[6];
  const float* bhh = (const float*)d_in[7];
  float* out = (float*)d_out;

  char* ws = (char*)d_ws;
  f16* W16 = (f16*)ws;                   // 1,048,576 B
  float* bias = (float*)(ws + 1048576);  // 4,096 B
  u32* hx = (u32*)(ws + 1052672);        // 262,144 B (4 parity x 16384 u32)
  f16* embed16 = (f16*)(ws + 1314816);   // 16,384,000 B
  const size_t WS_NEED = 1314816 + 16384000;

  convert_k<<<2048, 256, 0, stream>>>(Wih, Whh, bih, bhh, W16, bias, hx);
  if (ws_size >= WS_NEED) {
    convert_embed_k<<<4000, 256, 0, stream>>>(embed, embed16);
    lstm_k<1><<<16, 256, 0, stream>>>(W16, bias, text, embed, embed16, mask, out, hx);
  } else {
    lstm_k<0><<<16, 256, 0, stream>>>(W16, bias, text, embed, embed16, mask, out, hx);
  }
}